// Round 10
// baseline (19.375 us; speedup 1.0000x reference)
//
#include <hip/hip_runtime.h>
#include <math.h>

// ---------------------------------------------------------------------------
// StageALoss (FCOS-like): conf focal over all locations, CIoU over in-box,
// quality BCE at argmin-dist location per (level,batch).
//
// R9 -> R10: load-balance the grid. lvl0 (76% of locations) was 128 blocks on
// a 256-CU chip -> half the machine idled on the critical path. Now 512
// blocks x 1024 threads: 256 lvl0 half-batch blocks (dispatch puts one on
// every CU) + 128 lvl1 + 128 lvl2 slot-owners finalized in-kernel. lvl0
// slots pair-combine + q8-gather in fin_k (512 parallel gathers, 1/thread).
// Focal rewritten as a_t*sigma(u)^2*softplus(u), u=(1-2t)z (exact, fewer ops).
// Two kernels, no atomics, no fences (R4: device-scope sync ~50us on CDNA).
// ---------------------------------------------------------------------------

#define NBLK 512   // 256 lvl0 halves + 128 lvl1 + 128 lvl2

__device__ __forceinline__ float rcpf(float x) { return __builtin_amdgcn_rcpf(x); }

__device__ __forceinline__ float logsigf(float x) {
    return fminf(x, 0.f) - __logf(1.f + __expf(-fabsf(x)));
}

// CIoU + argmin update for one in-box location.
__device__ __forceinline__ void ciou_one(
    float cx, float cy, float stride, float ls, float ts, float rs, float bs,
    float x1, float y1, float x2, float y2, float bcx, float bcy, int locj,
    float& ciou, int& np, unsigned long long& pk)
{
    const float pl  = __expf(fminf(fmaxf(ls, -6.f), 6.f)) * stride;
    const float pt_ = __expf(fminf(fmaxf(ts, -6.f), 6.f)) * stride;
    const float pr  = __expf(fminf(fmaxf(rs, -6.f), 6.f)) * stride;
    const float pb  = __expf(fminf(fmaxf(bs, -6.f), 6.f)) * stride;
    const float gl  = cx - x1, gtl = cy - y1, gr = x2 - cx, gb = y2 - cy;
    const float pw = pl + pr, ph = pt_ + pb;
    const float gw = gl + gr, gh = gtl + gb;
    const float iw = fmaxf(fminf(pl, gl) + fminf(pr, gr), 0.f);
    const float ih = fmaxf(fminf(pt_, gtl) + fminf(pb, gb), 0.f);
    const float inter = iw * ih;
    const float uni   = pw * ph + gw * gh - inter + 1e-6f;
    const float iou   = inter * rcpf(uni);
    const float cw_ = fmaxf(pl, gl) + fmaxf(pr, gr);
    const float ch_ = fmaxf(pt_, gtl) + fmaxf(pb, gb);
    const float c2  = cw_ * cw_ + ch_ * ch_ + 1e-6f;
    const float dcx = 0.5f * (pr - pl) - 0.5f * (gr - gl);
    const float dcy = 0.5f * (pb - pt_) - 0.5f * (gb - gtl);
    const float rho2 = dcx * dcx + dcy * dcy;
    const float dv = atanf(gw * rcpf(gh + 1e-6f)) - atanf(pw * rcpf(ph + 1e-6f));
    const float v  = (4.f / (float)(M_PI * M_PI)) * dv * dv;
    const float alpha = v * rcpf(1.f - iou + v + 1e-6f);
    ciou += 1.f - iou + rho2 * rcpf(c2) + alpha * v;
    ++np;
    const float ddx = cx - bcx, ddy = cy - bcy;
    const float dist2 = ddx * ddx + ddy * ddy;
    const unsigned long long cand =
        ((unsigned long long)__float_as_uint(dist2) << 32) | (unsigned)locj;
    pk = cand < pk ? cand : pk;  // min -> first-index tie-break (argmin)
}

// Focal: a_t * sigmoid(u)^2 * softplus(u), u = (1-2t)z  (exact rewrite).
__device__ __forceinline__ void focal4(const float4& d0, const bool inb[4], float& conf)
{
    const float zs[4] = { d0.x, d0.y, d0.z, d0.w };
    #pragma unroll
    for (int j = 0; j < 4; ++j) {
        const float u   = inb[j] ? -zs[j] : zs[j];
        const float e   = __expf(-fabsf(u));          // (0, 1]
        const float ope = 1.f + e;
        const float L   = __logf(ope);
        const float inv = rcpf(ope);
        const float sg  = (u >= 0.f) ? inv : e * inv; // sigmoid(u)
        const float sp  = fmaxf(u, 0.f) + L;          // softplus(u) = ce
        const float at  = inb[j] ? 0.25f : 0.75f;
        conf += at * sg * sg * sp;
    }
}

// One 4-loc stripe; ltrb loads issued before focal so latency hides under it.
__device__ __forceinline__ void stripe4(
    const float* __restrict__ det, size_t c0base, int loc, size_t HW, float stride,
    const float cxs[4], const bool cxok[4], float cy,
    float x1, float y1, float x2, float y2, float bcx, float bcy,
    const float4& d0, float& conf, float& ciou, int& np, unsigned long long& pk)
{
    const bool cyok = (cy > y1) & (cy < y2);
    bool inb[4]; bool anyb = false;
    #pragma unroll
    for (int j = 0; j < 4; ++j) { inb[j] = cxok[j] & cyok; anyb |= inb[j]; }
    const bool wa = __any(anyb);     // wave-uniform

    float4 d1, d2, d3, d4;
    if (wa) {
        d1 = *(const float4*)(det + c0base + HW + (size_t)loc);
        d2 = *(const float4*)(det + c0base + 2 * HW + (size_t)loc);
        d3 = *(const float4*)(det + c0base + 3 * HW + (size_t)loc);
        d4 = *(const float4*)(det + c0base + 4 * HW + (size_t)loc);
    }

    focal4(d0, inb, conf);

    if (wa) {
        const float ls[4] = { d1.x, d1.y, d1.z, d1.w };
        const float ts[4] = { d2.x, d2.y, d2.z, d2.w };
        const float rs[4] = { d3.x, d3.y, d3.z, d3.w };
        const float bs[4] = { d4.x, d4.y, d4.z, d4.w };
        #pragma unroll
        for (int j = 0; j < 4; ++j)
            if (inb[j])
                ciou_one(cxs[j], cy, stride, ls[j], ts[j], rs[j], bs[j],
                         x1, y1, x2, y2, bcx, bcy, loc + j, ciou, np, pk);
    }
}

// 512 blocks x 1024 threads:
//   bid <  256 : lvl0, b = bid>>1, half = bid&1 -> 8192 locs (2 stripes) -> partials
//   256..383   : lvl1, b = bid-256, 4096 locs (1 stripe), slot-owned -> finalized
//   384..511   : lvl2, b = bid-384, 1024 locs (threads 0..255), slot-owned -> finalized
__global__ __launch_bounds__(1024) void level_k(
    const float* __restrict__ det8, const float* __restrict__ det16, const float* __restrict__ det32,
    const float* __restrict__ q16, const float* __restrict__ q32,
    const float* __restrict__ gtb, const float* __restrict__ gtq,
    float4* __restrict__ contrib,
    unsigned long long* __restrict__ pk_p, float* __restrict__ ciou_p, int* __restrict__ np_p)
{
    const int tid = (int)threadIdx.x;
    const int bid = (int)blockIdx.x;

    int b, base, log2W, l2q, nstripe;
    const float* det; const float* q; float stride; float inv_denom; size_t HW;
    bool active = true, owner = false;
    if (bid < 256) {
        b = bid >> 1; base = (bid & 1) * 8192; det = det8; q = nullptr;
        stride = 8.f;  log2W = 7; HW = 16384; l2q = 14; nstripe = 2; inv_denom = 1.f / 2097152.f;
    } else if (bid < 384) {
        b = bid - 256; base = 0; det = det16; q = q16; owner = true;
        stride = 16.f; log2W = 6; HW = 4096;  l2q = 12; nstripe = 1; inv_denom = 1.f / 524288.f;
    } else {
        b = bid - 384; base = 0; det = det32; q = q32; owner = true;
        stride = 32.f; log2W = 5; HW = 1024;  l2q = 10; nstripe = 1; inv_denom = 1.f / 131072.f;
        active = (tid < 256);
    }

    const float4 gq = owner ? *(const float4*)(gtq + b * 4) : make_float4(0, 0, 0, 0);

    float conf = 0.f, ciou = 0.f; int np = 0;
    unsigned long long pk = ~0ULL;

    const float x1 = gtb[b * 4 + 0];
    if (x1 >= 0.f && active) {  // invalid batch contributes exactly 0
        const float y1 = gtb[b * 4 + 1];
        const float x2 = gtb[b * 4 + 2];
        const float y2 = gtb[b * 4 + 3];
        const float bcx = 0.5f * (x1 + x2);
        const float bcy = 0.5f * (y1 + y2);
        const size_t c0base = (size_t)(b * 5) * HW;
        const int Wm1 = (1 << log2W) - 1;
        const int loc0 = base + (tid << 2);

        // stripe-invariant: xi, cxs, cx-range tests (stripes are row multiples)
        const int xi = loc0 & Wm1;
        float cxs[4]; bool cxok[4];
        #pragma unroll
        for (int j = 0; j < 4; ++j) {
            cxs[j]  = ((float)(xi + j) + 0.5f) * stride;
            cxok[j] = (cxs[j] > x1) & (cxs[j] < x2);
        }
        float cy = ((float)(loc0 >> log2W) + 0.5f) * stride;

        if (nstripe == 2) {
            const float dcy = stride * (float)(4096 >> log2W);  // rows/stripe * stride
            const float4 dA = *(const float4*)(det + c0base + (size_t)loc0);
            const float4 dB = *(const float4*)(det + c0base + (size_t)(loc0 + 4096));
            stripe4(det, c0base, loc0, HW, stride, cxs, cxok, cy,
                    x1, y1, x2, y2, bcx, bcy, dA, conf, ciou, np, pk);
            stripe4(det, c0base, loc0 + 4096, HW, stride, cxs, cxok, cy + dcy,
                    x1, y1, x2, y2, bcx, bcy, dB, conf, ciou, np, pk);
        } else {
            const float4 d0 = *(const float4*)(det + c0base + (size_t)loc0);
            stripe4(det, c0base, loc0, HW, stride, cxs, cxok, cy,
                    x1, y1, x2, y2, bcx, bcy, d0, conf, ciou, np, pk);
        }
        conf *= inv_denom;
    }

    // wave (64-lane) shuffle reduction
    #pragma unroll
    for (int off = 32; off > 0; off >>= 1) {
        conf += __shfl_down(conf, off);
        ciou += __shfl_down(ciou, off);
        np   += __shfl_down(np, off);
        unsigned long long o = __shfl_down(pk, off);
        pk = o < pk ? o : pk;
    }

    // cross-wave (16 waves) via LDS
    __shared__ float s_conf[16], s_ciou[16];
    __shared__ int   s_np[16];
    __shared__ unsigned long long s_pk[16];
    const int wid = tid >> 6;
    if ((tid & 63) == 0) {
        s_conf[wid] = conf; s_ciou[wid] = ciou; s_np[wid] = np; s_pk[wid] = pk;
    }
    __syncthreads();
    if (tid == 0) {
        float cf = 0.f, ci = 0.f; int nt = 0;
        unsigned long long mn = ~0ULL;
        #pragma unroll
        for (int w = 0; w < 16; ++w) {
            cf += s_conf[w]; ci += s_ciou[w]; nt += s_np[w];
            mn = s_pk[w] < mn ? s_pk[w] : mn;
        }
        if (!owner) {       // lvl0 half-batch: partials, combined in fin_k
            pk_p[bid] = mn; ciou_p[bid] = ci; np_p[bid] = nt;
            contrib[bid] = make_float4(cf, 0.f, 0.f, 0.f);
        } else {            // lvl1/lvl2: finalize slot in-kernel
            float bbv = 0.f, qlv = 0.f, flag = 0.f;
            if (nt > 0) {
                bbv = ci * rcpf((float)nt);
                const unsigned idx = (unsigned)(mn & 0xffffffffULL);
                const float gqs[4] = { gq.x, gq.y, gq.z, gq.w };
                float s = 0.f;
                #pragma unroll
                for (int c = 0; c < 4; ++c) {
                    const float best = q[((size_t)(b * 4 + c) << l2q) + idx];
                    const float qt = fminf(fmaxf(gqs[c], 0.05f), 0.95f);
                    s -= qt * logsigf(best) + (1.f - qt) * logsigf(-best);
                }
                qlv = 0.25f * s;   // bce.mean over C_Q=4
                flag = 1.f;        // has_pos
            }
            contrib[bid] = make_float4(cf, bbv, qlv, flag);
        }
    }
}

// Finisher: 512 contribs + 128 lvl0 pair-combines + 512 parallel q8 gathers.
__global__ __launch_bounds__(512) void fin_k(
    const float* __restrict__ q8, const float* __restrict__ gtq,
    const float4* __restrict__ contrib,
    const unsigned long long* __restrict__ pk_p, const float* __restrict__ ciou_p,
    const int* __restrict__ np_p,
    float* __restrict__ out)
{
    const int i = threadIdx.x;
    __shared__ unsigned sidx[128];   // lvl0 slot argmin (0xFFFFFFFF = no pos)

    const float4 v = contrib[i];
    float cf = v.x, bb = v.y, ql = v.z, nf = v.w;

    if (i < 128) {  // combine the two lvl0 half-batch partials
        const float ci = ciou_p[2 * i] + ciou_p[2 * i + 1];
        const int   np = np_p[2 * i] + np_p[2 * i + 1];
        unsigned long long mn = pk_p[2 * i];
        const unsigned long long p1 = pk_p[2 * i + 1];
        mn = p1 < mn ? p1 : mn;
        if (np > 0) {
            bb += ci * rcpf((float)np);
            nf += 1.f;
            sidx[i] = (unsigned)(mn & 0xffffffffULL);
        } else {
            sidx[i] = 0xFFFFFFFFu;
        }
    }
    __syncthreads();

    // 512 q8 gathers, one per thread (slot s = i>>2, channel c = i&3)
    {
        const int s = i >> 2, c = i & 3;
        const unsigned idx = sidx[s];
        float term = 0.f;
        if (idx != 0xFFFFFFFFu) {
            const float best = q8[((size_t)(s * 4 + c) << 14) + idx];
            const float qt = fminf(fmaxf(gtq[s * 4 + c], 0.05f), 0.95f);
            term = -(qt * logsigf(best) + (1.f - qt) * logsigf(-best));
        }
        term += __shfl_down(term, 2);
        term += __shfl_down(term, 1);
        if (c == 0) ql += 0.25f * term;
    }

    // wave shuffle reduce, then one LDS round
    #pragma unroll
    for (int off = 32; off > 0; off >>= 1) {
        cf += __shfl_down(cf, off);
        bb += __shfl_down(bb, off);
        ql += __shfl_down(ql, off);
        nf += __shfl_down(nf, off);
    }
    __shared__ float wc[8], wb[8], wq[8], wn[8];
    if ((i & 63) == 0) { wc[i >> 6] = cf; wb[i >> 6] = bb; wq[i >> 6] = ql; wn[i >> 6] = nf; }
    __syncthreads();
    if (i == 0) {
        float conf_t = 0.f, tb0 = 0.f, tq0 = 0.f, nsum = 0.f;
        #pragma unroll
        for (int w = 0; w < 8; ++w) { conf_t += wc[w]; tb0 += wb[w]; tq0 += wq[w]; nsum += wn[w]; }
        const int ntot = (int)(nsum + 0.5f);
        const float denom = fmaxf((float)ntot, 1.f);
        const float tb = (ntot > 0) ? tb0 / denom : tb0;
        const float tq = (ntot > 0) ? tq0 / denom : tq0;
        out[0] = conf_t + 5.f * tb + 0.05f * tq;
        out[1] = conf_t;
        out[2] = tb;
        out[3] = tq;
    }
}

extern "C" void kernel_launch(void* const* d_in, const int* in_sizes, int n_in,
                              void* d_out, int out_size, void* d_ws, size_t ws_size,
                              hipStream_t stream) {
    const float* det8  = (const float*)d_in[0];
    const float* det16 = (const float*)d_in[1];
    const float* det32 = (const float*)d_in[2];
    const float* q8    = (const float*)d_in[3];
    const float* q16   = (const float*)d_in[4];
    const float* q32   = (const float*)d_in[5];
    const float* gtb   = (const float*)d_in[6];
    const float* gtq   = (const float*)d_in[7];
    float* out = (float*)d_out;

    // workspace: contrib 512*16=8192 | pk_p 256*8=2048 | ciou_p 256*4 | np_p 256*4
    float4* contrib = (float4*)d_ws;
    unsigned long long* pk_p = (unsigned long long*)((char*)d_ws + 8192);
    float* ciou_p = (float*)((char*)d_ws + 10240);
    int*   np_p   = (int*)((char*)d_ws + 11264);

    hipLaunchKernelGGL(level_k, dim3(NBLK), dim3(1024), 0, stream,
                       det8, det16, det32, q16, q32, gtb, gtq,
                       contrib, pk_p, ciou_p, np_p);
    hipLaunchKernelGGL(fin_k, dim3(1), dim3(512), 0, stream,
                       q8, gtq, contrib, pk_p, ciou_p, np_p, out);
}

// Round 11
// 17.970 us; speedup vs baseline: 1.0782x; 1.0782x over previous
//
#include <hip/hip_runtime.h>
#include <math.h>

// ---------------------------------------------------------------------------
// StageALoss (FCOS-like): conf focal over all locations, CIoU over in-box,
// quality BCE at argmin-dist location per (level,batch).
//
// R10 -> R11: REVERT to the R9 structure (best measured, 18.15us). R10's
// lvl0 2-way split regressed (-1.2us): halved per-thread MLP depth + heavier
// fin_k tail outweighed the balance gain. Kept from R10: exact focal rewrite
// a_t*sigma(u)^2*softplus(u), u=(1-2t)z (~4 fewer VALU/loc, same math).
// Structure: 384 blocks x 1024 threads, every block owns one (level,batch)
// slot and finalizes it in-kernel; fin_k is a single 64-lane wave over 384
// float4 contribs. Two kernels, no atomics, no fences (R4: device-scope sync
// ~50us on multi-XCD CDNA). History: R1 138us (atomic stall) -> R3 22 ->
// R8 18.2 -> R9 18.1 (plateau; launch machinery + latency floor).
// ---------------------------------------------------------------------------

#define NBLK 384   // lvl0: 128 (1/batch), lvl1: 128, lvl2: 128

__device__ __forceinline__ float rcpf(float x) { return __builtin_amdgcn_rcpf(x); }

__device__ __forceinline__ float logsigf(float x) {
    return fminf(x, 0.f) - __logf(1.f + __expf(-fabsf(x)));
}

// CIoU + argmin update for one in-box location.
__device__ __forceinline__ void ciou_one(
    float cx, float cy, float stride, float ls, float ts, float rs, float bs,
    float x1, float y1, float x2, float y2, float bcx, float bcy, int locj,
    float& ciou, int& np, unsigned long long& pk)
{
    const float pl  = __expf(fminf(fmaxf(ls, -6.f), 6.f)) * stride;
    const float pt_ = __expf(fminf(fmaxf(ts, -6.f), 6.f)) * stride;
    const float pr  = __expf(fminf(fmaxf(rs, -6.f), 6.f)) * stride;
    const float pb  = __expf(fminf(fmaxf(bs, -6.f), 6.f)) * stride;
    const float gl  = cx - x1, gtl = cy - y1, gr = x2 - cx, gb = y2 - cy;
    const float pw = pl + pr, ph = pt_ + pb;
    const float gw = gl + gr, gh = gtl + gb;
    const float iw = fmaxf(fminf(pl, gl) + fminf(pr, gr), 0.f);
    const float ih = fmaxf(fminf(pt_, gtl) + fminf(pb, gb), 0.f);
    const float inter = iw * ih;
    const float uni   = pw * ph + gw * gh - inter + 1e-6f;
    const float iou   = inter * rcpf(uni);
    const float cw_ = fmaxf(pl, gl) + fmaxf(pr, gr);
    const float ch_ = fmaxf(pt_, gtl) + fmaxf(pb, gb);
    const float c2  = cw_ * cw_ + ch_ * ch_ + 1e-6f;
    const float dcx = 0.5f * (pr - pl) - 0.5f * (gr - gl);
    const float dcy = 0.5f * (pb - pt_) - 0.5f * (gb - gtl);
    const float rho2 = dcx * dcx + dcy * dcy;
    const float dv = atanf(gw * rcpf(gh + 1e-6f)) - atanf(pw * rcpf(ph + 1e-6f));
    const float v  = (4.f / (float)(M_PI * M_PI)) * dv * dv;
    const float alpha = v * rcpf(1.f - iou + v + 1e-6f);
    ciou += 1.f - iou + rho2 * rcpf(c2) + alpha * v;
    ++np;
    const float ddx = cx - bcx, ddy = cy - bcy;
    const float dist2 = ddx * ddx + ddy * ddy;
    const unsigned long long cand =
        ((unsigned long long)__float_as_uint(dist2) << 32) | (unsigned)locj;
    pk = cand < pk ? cand : pk;  // min -> first-index tie-break (argmin)
}

// Focal: a_t * sigmoid(u)^2 * softplus(u), u = (1-2t)z  (exact rewrite).
__device__ __forceinline__ void focal4(const float4& d0, const bool inb[4], float& conf)
{
    const float zs[4] = { d0.x, d0.y, d0.z, d0.w };
    #pragma unroll
    for (int j = 0; j < 4; ++j) {
        const float u   = inb[j] ? -zs[j] : zs[j];
        const float e   = __expf(-fabsf(u));          // (0, 1]
        const float ope = 1.f + e;
        const float L   = __logf(ope);
        const float inv = rcpf(ope);
        const float sg  = (u >= 0.f) ? inv : e * inv; // sigmoid(u)
        const float sp  = fmaxf(u, 0.f) + L;          // softplus(u) = ce
        const float at  = inb[j] ? 0.25f : 0.75f;
        conf += at * sg * sg * sp;
    }
}

// One 4-loc stripe; ltrb loads issued before focal so latency hides under it.
__device__ __forceinline__ void stripe4(
    const float* __restrict__ det, size_t c0base, int loc, size_t HW, float stride,
    const float cxs[4], const bool cxok[4], float cy,
    float x1, float y1, float x2, float y2, float bcx, float bcy,
    const float4& d0, float& conf, float& ciou, int& np, unsigned long long& pk)
{
    const bool cyok = (cy > y1) & (cy < y2);
    bool inb[4]; bool anyb = false;
    #pragma unroll
    for (int j = 0; j < 4; ++j) { inb[j] = cxok[j] & cyok; anyb |= inb[j]; }
    const bool wa = __any(anyb);     // wave-uniform

    float4 d1, d2, d3, d4;
    if (wa) {                        // issue loads first
        d1 = *(const float4*)(det + c0base + HW + (size_t)loc);
        d2 = *(const float4*)(det + c0base + 2 * HW + (size_t)loc);
        d3 = *(const float4*)(det + c0base + 3 * HW + (size_t)loc);
        d4 = *(const float4*)(det + c0base + 4 * HW + (size_t)loc);
    }

    focal4(d0, inb, conf);           // latency of d1..d4 hides under this

    if (wa) {
        const float ls[4] = { d1.x, d1.y, d1.z, d1.w };
        const float ts[4] = { d2.x, d2.y, d2.z, d2.w };
        const float rs[4] = { d3.x, d3.y, d3.z, d3.w };
        const float bs[4] = { d4.x, d4.y, d4.z, d4.w };
        #pragma unroll
        for (int j = 0; j < 4; ++j)
            if (inb[j])
                ciou_one(cxs[j], cy, stride, ls[j], ts[j], rs[j], bs[j],
                         x1, y1, x2, y2, bcx, bcy, loc + j, ciou, np, pk);
    }
}

// 384 blocks x 1024 threads; every block owns one (level,batch) slot:
//   bid <  128 : lvl0, b = bid,     16384 locs = 4 stripes x 4 locs/thread
//   128..255   : lvl1, b = bid-128,  4096 locs = 1 stripe
//   256..383   : lvl2, b = bid-256,  1024 locs = 1 stripe on threads 0..255
__global__ __launch_bounds__(1024) void level_k(
    const float* __restrict__ det8, const float* __restrict__ det16, const float* __restrict__ det32,
    const float* __restrict__ q8, const float* __restrict__ q16, const float* __restrict__ q32,
    const float* __restrict__ gtb, const float* __restrict__ gtq,
    float4* __restrict__ contrib)
{
    const int tid = (int)threadIdx.x;
    const int bid = (int)blockIdx.x;

    int b, log2W, l2q, nstripe;
    const float* det; const float* q; float stride; float inv_denom; size_t HW;
    bool active = true;
    if (bid < 128) {
        b = bid; det = det8; q = q8;
        stride = 8.f;  log2W = 7; HW = 16384; l2q = 14; nstripe = 4; inv_denom = 1.f / 2097152.f;
    } else if (bid < 256) {
        b = bid - 128; det = det16; q = q16;
        stride = 16.f; log2W = 6; HW = 4096;  l2q = 12; nstripe = 1; inv_denom = 1.f / 524288.f;
    } else {
        b = bid - 256; det = det32; q = q32;
        stride = 32.f; log2W = 5; HW = 1024;  l2q = 10; nstripe = 1; inv_denom = 1.f / 131072.f;
        active = (tid < 256);
    }

    // uniform loads issued up-front (s_load; consumed ~4000cy later)
    const float4 gq = *(const float4*)(gtq + b * 4);

    float conf = 0.f, ciou = 0.f; int np = 0;
    unsigned long long pk = ~0ULL;

    const float x1 = gtb[b * 4 + 0];
    if (x1 >= 0.f && active) {  // invalid batch contributes exactly 0
        const float y1 = gtb[b * 4 + 1];
        const float x2 = gtb[b * 4 + 2];
        const float y2 = gtb[b * 4 + 3];
        const float bcx = 0.5f * (x1 + x2);
        const float bcy = 0.5f * (y1 + y2);
        const size_t c0base = (size_t)(b * 5) * HW;
        const int Wm1 = (1 << log2W) - 1;
        const int loc0 = tid << 2;

        // stripe-invariant: xi, cxs, cx-range tests (stripes are row multiples)
        const int xi = loc0 & Wm1;
        float cxs[4]; bool cxok[4];
        #pragma unroll
        for (int j = 0; j < 4; ++j) {
            cxs[j]  = ((float)(xi + j) + 0.5f) * stride;
            cxok[j] = (cxs[j] > x1) & (cxs[j] < x2);
        }
        float cy = ((float)(loc0 >> log2W) + 0.5f) * stride;

        if (nstripe == 4) {
            const float dcy = stride * (float)(4096 >> log2W);  // rows/stripe * stride
            float4 d[4];
            #pragma unroll
            for (int s = 0; s < 4; ++s)   // all 4 d0 loads issued up front (4x MLP)
                d[s] = *(const float4*)(det + c0base + (size_t)(loc0 + s * 4096));
            #pragma unroll
            for (int s = 0; s < 4; ++s) {
                stripe4(det, c0base, loc0 + s * 4096, HW, stride, cxs, cxok, cy,
                        x1, y1, x2, y2, bcx, bcy, d[s], conf, ciou, np, pk);
                cy += dcy;
            }
        } else {
            const float4 d0 = *(const float4*)(det + c0base + (size_t)loc0);
            stripe4(det, c0base, loc0, HW, stride, cxs, cxok, cy,
                    x1, y1, x2, y2, bcx, bcy, d0, conf, ciou, np, pk);
        }
        conf *= inv_denom;
    }

    // wave (64-lane) shuffle reduction
    #pragma unroll
    for (int off = 32; off > 0; off >>= 1) {
        conf += __shfl_down(conf, off);
        ciou += __shfl_down(ciou, off);
        np   += __shfl_down(np, off);
        unsigned long long o = __shfl_down(pk, off);
        pk = o < pk ? o : pk;
    }

    // cross-wave (16 waves) via LDS
    __shared__ float s_conf[16], s_ciou[16];
    __shared__ int   s_np[16];
    __shared__ unsigned long long s_pk[16];
    const int wid = tid >> 6;
    if ((tid & 63) == 0) {
        s_conf[wid] = conf; s_ciou[wid] = ciou; s_np[wid] = np; s_pk[wid] = pk;
    }
    __syncthreads();
    if (tid == 0) {
        float cf = 0.f, ci = 0.f; int nt = 0;
        unsigned long long mn = ~0ULL;
        #pragma unroll
        for (int w = 0; w < 16; ++w) {
            cf += s_conf[w]; ci += s_ciou[w]; nt += s_np[w];
            mn = s_pk[w] < mn ? s_pk[w] : mn;
        }
        // slot finalization in-kernel: ciou_mean + qual BCE gather + has_pos
        float bbv = 0.f, qlv = 0.f, flag = 0.f;
        if (nt > 0) {
            bbv = ci * rcpf((float)nt);
            const unsigned idx = (unsigned)(mn & 0xffffffffULL);
            const float gqs[4] = { gq.x, gq.y, gq.z, gq.w };
            float s = 0.f;
            #pragma unroll
            for (int c = 0; c < 4; ++c) {
                const float best = q[((size_t)(b * 4 + c) << l2q) + idx];
                const float qt = fminf(fmaxf(gqs[c], 0.05f), 0.95f);
                s -= qt * logsigf(best) + (1.f - qt) * logsigf(-best);
            }
            qlv = 0.25f * s;   // bce.mean over C_Q=4
            flag = 1.f;        // has_pos
        }
        contrib[bid] = make_float4(cf, bbv, qlv, flag);
    }
}

// Single-wave finisher: 384 float4 (6 KB) -> 4 outputs. No LDS, no barriers.
__global__ __launch_bounds__(64) void fin_k(
    const float4* __restrict__ contrib, float* __restrict__ out)
{
    const int i = threadIdx.x;
    float cf = 0.f, bb = 0.f, ql = 0.f, nf = 0.f;
    #pragma unroll
    for (int k = 0; k < 6; ++k) {           // 6 * 64 = 384
        const float4 v = contrib[k * 64 + i];
        cf += v.x; bb += v.y; ql += v.z; nf += v.w;
    }
    #pragma unroll
    for (int off = 32; off > 0; off >>= 1) {
        cf += __shfl_down(cf, off);
        bb += __shfl_down(bb, off);
        ql += __shfl_down(ql, off);
        nf += __shfl_down(nf, off);
    }
    if (i == 0) {
        const int ntot = (int)(nf + 0.5f);
        const float denom = fmaxf((float)ntot, 1.f);
        const float tb = (ntot > 0) ? bb / denom : bb;
        const float tq = (ntot > 0) ? ql / denom : ql;
        out[0] = cf + 5.f * tb + 0.05f * tq;
        out[1] = cf;
        out[2] = tb;
        out[3] = tq;
    }
}

extern "C" void kernel_launch(void* const* d_in, const int* in_sizes, int n_in,
                              void* d_out, int out_size, void* d_ws, size_t ws_size,
                              hipStream_t stream) {
    const float* det8  = (const float*)d_in[0];
    const float* det16 = (const float*)d_in[1];
    const float* det32 = (const float*)d_in[2];
    const float* q8    = (const float*)d_in[3];
    const float* q16   = (const float*)d_in[4];
    const float* q32   = (const float*)d_in[5];
    const float* gtb   = (const float*)d_in[6];
    const float* gtq   = (const float*)d_in[7];
    float* out = (float*)d_out;

    float4* contrib = (float4*)d_ws;   // 384 * 16 = 6144 bytes

    hipLaunchKernelGGL(level_k, dim3(NBLK), dim3(1024), 0, stream,
                       det8, det16, det32, q8, q16, q32, gtb, gtq, contrib);
    hipLaunchKernelGGL(fin_k, dim3(1), dim3(64), 0, stream,
                       contrib, out);
}